// Round 1
// baseline (707.425 us; speedup 1.0000x reference)
//
#include <hip/hip_runtime.h>

// Problem constants (from reference): B=4, C=64, N=512*512, K=400
constexpr int BB   = 4;
constexpr int CC   = 64;
constexpr int NPIX = 512 * 512;      // 262144
constexpr int KK   = 400;

constexpr int CH     = 32;           // channels per accumulate pass (2 halves)
constexpr int PPB    = 4096;         // pixels per block
constexpr int STRIDE = CH + 1;       // 33: bank = (k*33+c)%32 = (k+c)%32 -> spread
constexpr int ATHREADS = 512;

// ---------------------------------------------------------------------------
// Stage 1: per-block LDS histogram of [K x 32ch], merged to global with atomics
// grid = B * 64 chunks * 2 channel-halves = 512 blocks
// ---------------------------------------------------------------------------
__global__ __launch_bounds__(ATHREADS) void accum_kernel(
    const float* __restrict__ feat,   // [B, C, N]
    const int*   __restrict__ idx,    // [B, N]
    float* __restrict__ g_sums,       // [B, K, C]
    float* __restrict__ g_cnt)        // [B, K]
{
    __shared__ float s_sums[KK * STRIDE];          // 52800 B
    __shared__ float s_cnt[KK];                    //  1600 B
    __shared__ alignas(16) unsigned short s_idx[PPB]; // 8192 B  (k*33 premultiplied)

    const int t     = threadIdx.x;
    const int blk   = blockIdx.x;
    const int chalf = blk & 1;
    const int chunk = (blk >> 1) & 63;
    const int b     = blk >> 7;
    const int p0    = chunk * PPB;

    // zero LDS
    for (int i = t; i < KK * STRIDE; i += ATHREADS) s_sums[i] = 0.0f;
    if (chalf == 0)
        for (int i = t; i < KK; i += ATHREADS) s_cnt[i] = 0.0f;
    __syncthreads();

    // load idx chunk, premultiply by STRIDE; counts only in chalf==0 blocks
    const int* idx_b = idx + b * NPIX + p0;
    for (int i = t; i < PPB; i += ATHREADS) {
        int k = idx_b[i];
        s_idx[i] = (unsigned short)(k * STRIDE);
        if (chalf == 0) atomicAdd(&s_cnt[k], 1.0f);
    }
    __syncthreads();

    // accumulate: for each of 32 channels, float4 over pixels
    const float* fb = feat + (size_t)b * CC * NPIX + (size_t)(chalf * CH) * NPIX + p0;
    for (int c = 0; c < CH; ++c) {
        const float4* f4 = (const float4*)(fb + (size_t)c * NPIX);
        const ushort4* k4 = (const ushort4*)s_idx;
#pragma unroll
        for (int j = 0; j < PPB / 4 / ATHREADS; ++j) {   // 2 iterations
            int i4 = j * ATHREADS + t;
            float4  v  = f4[i4];
            ushort4 kk = k4[i4];
            atomicAdd(&s_sums[kk.x + c], v.x);
            atomicAdd(&s_sums[kk.y + c], v.y);
            atomicAdd(&s_sums[kk.z + c], v.z);
            atomicAdd(&s_sums[kk.w + c], v.w);
        }
    }
    __syncthreads();

    // merge to global
    float* gs = g_sums + ((size_t)b * KK) * CC + chalf * CH;
    for (int e = t; e < KK * CH; e += ATHREADS) {
        int k = e >> 5;        // CH = 32
        int c = e & 31;
        float v = s_sums[k * STRIDE + c];
        if (v != 0.0f) atomicAdd(&gs[k * CC + c], v);
    }
    if (chalf == 0) {
        for (int k = t; k < KK; k += ATHREADS) {
            float v = s_cnt[k];
            if (v != 0.0f) atomicAdd(&g_cnt[b * KK + k], v);
        }
    }
}

// ---------------------------------------------------------------------------
// Stage 2: in-place sums -> means
// ---------------------------------------------------------------------------
__global__ __launch_bounds__(256) void means_kernel(float* __restrict__ g_sums,
                                                    const float* __restrict__ g_cnt)
{
    int e = blockIdx.x * 256 + threadIdx.x;
    if (e < BB * KK * CC) {
        float cnt = g_cnt[e >> 6];           // C = 64
        g_sums[e] = g_sums[e] / fmaxf(cnt, 1.0f);
    }
}

// ---------------------------------------------------------------------------
// Stage 3: gather means back to pixels. thread = 4 consecutive pixels,
// register-transpose 4 mean-rows -> coalesced float4 stores per channel.
// grid = B * 256 blocks, 256 threads
// ---------------------------------------------------------------------------
__global__ __launch_bounds__(256) void gather_kernel(
    const float* __restrict__ means,  // [B, K, C]
    const int*   __restrict__ idx,    // [B, N]
    float* __restrict__ out)          // [B, C, N]
{
    const int t   = threadIdx.x;
    const int blk = blockIdx.x;
    const int b   = blk >> 8;
    const int n0  = (((blk & 255) << 8) + t) << 2;   // pixel group start

    int4 kk = *(const int4*)(idx + b * NPIX + n0);
    const float4* m4 = (const float4*)means;
    const size_t rbase = (size_t)b * KK * (CC / 4);
    const float4* r0 = m4 + rbase + (size_t)kk.x * (CC / 4);
    const float4* r1 = m4 + rbase + (size_t)kk.y * (CC / 4);
    const float4* r2 = m4 + rbase + (size_t)kk.z * (CC / 4);
    const float4* r3 = m4 + rbase + (size_t)kk.w * (CC / 4);

    float* ob = out + (size_t)b * CC * NPIX + n0;
#pragma unroll
    for (int cg = 0; cg < CC / 4; ++cg) {
        float4 a = r0[cg], bv = r1[cg], cv = r2[cg], dv = r3[cg];
        float4 o0 = {a.x, bv.x, cv.x, dv.x};
        float4 o1 = {a.y, bv.y, cv.y, dv.y};
        float4 o2 = {a.z, bv.z, cv.z, dv.z};
        float4 o3 = {a.w, bv.w, cv.w, dv.w};
        *(float4*)(ob + (size_t)(cg * 4 + 0) * NPIX) = o0;
        *(float4*)(ob + (size_t)(cg * 4 + 1) * NPIX) = o1;
        *(float4*)(ob + (size_t)(cg * 4 + 2) * NPIX) = o2;
        *(float4*)(ob + (size_t)(cg * 4 + 3) * NPIX) = o3;
    }
}

extern "C" void kernel_launch(void* const* d_in, const int* in_sizes, int n_in,
                              void* d_out, int out_size, void* d_ws, size_t ws_size,
                              hipStream_t stream) {
    const float* feat = (const float*)d_in[0];   // [B, C, N] fp32
    const int*   idx  = (const int*)d_in[1];     // [B, N] int32
    float* out    = (float*)d_out;               // [B, C, N] fp32
    float* g_sums = (float*)d_ws;                // B*K*C floats = 409600 B
    float* g_cnt  = g_sums + BB * KK * CC;       // B*K floats   =   6400 B

    hipMemsetAsync(d_ws, 0, (size_t)(BB * KK * CC + BB * KK) * sizeof(float), stream);

    accum_kernel<<<BB * 64 * 2, ATHREADS, 0, stream>>>(feat, idx, g_sums, g_cnt);
    means_kernel<<<(BB * KK * CC + 255) / 256, 256, 0, stream>>>(g_sums, g_cnt);
    gather_kernel<<<BB * 256, 256, 0, stream>>>(g_sums, idx, out);
}